// Round 10
// baseline (99.437 us; speedup 1.0000x reference)
//
#include <hip/hip_runtime.h>
#include <hip/hip_bf16.h>

#define N1 4096
#define N2 768
#define NCC 384
#define WS_NEEDED 100663296ull     // ws1 (50.3 MB bf16) + ws2 (50.3 MB bf16)
#define WS1_UINTS 12582912ull      // 8*64*3*8192
#define P1A_LDS 132096             // (64*386 + 64*130) uints * 4 B

__device__ __forceinline__ float2 cadd(float2 a, float2 b){ return make_float2(a.x+b.x, a.y+b.y); }
__device__ __forceinline__ float2 csub(float2 a, float2 b){ return make_float2(a.x-b.x, a.y-b.y); }
__device__ __forceinline__ float2 cmul(float2 a, float2 b){ return make_float2(a.x*b.x - a.y*b.y, a.x*b.y + a.y*b.x); }
__device__ __forceinline__ float2 cnegi(float2 a){ return make_float2(a.y, -a.x); }  // -i * a

// bf16x2 pack/unpack (RTN)
__device__ __forceinline__ unsigned pack_bf2(float2 v) {
  unsigned ax = __float_as_uint(v.x); ax = (ax + 0x7FFFu + ((ax >> 16) & 1u)) >> 16;
  unsigned ay = __float_as_uint(v.y); ay = (ay + 0x7FFFu + ((ay >> 16) & 1u)) & 0xFFFF0000u;
  return ax | ay;
}
__device__ __forceinline__ float2 unpack_bf2(unsigned u) {
  return make_float2(__uint_as_float(u << 16), __uint_as_float(u & 0xFFFF0000u));
}
__device__ __forceinline__ float bf2f(unsigned short u) {
  return __uint_as_float((unsigned)u << 16);
}

__device__ __forceinline__ int rev6(int p) {
  int k = 0;
  #pragma unroll
  for (int i = 0; i < 6; ++i) { k = (k << 2) | (p & 3); p >>= 2; }
  return k;
}

// In-register DIF FFT-8, natural-order outputs.
__device__ __forceinline__ void fft8(float2 z[8]) {
  const float RH = 0.70710678118654752f;
  float2 u0=cadd(z[0],z[4]), v0=csub(z[0],z[4]);
  float2 u1=cadd(z[1],z[5]), v1=csub(z[1],z[5]);
  float2 u2=cadd(z[2],z[6]), v2=csub(z[2],z[6]);
  float2 u3=cadd(z[3],z[7]), v3=csub(z[3],z[7]);
  v1 = make_float2(RH*(v1.x+v1.y), RH*(v1.y-v1.x));
  v2 = cnegi(v2);
  v3 = make_float2(RH*(v3.y-v3.x), -RH*(v3.x+v3.y));
  float2 a0=cadd(u0,u2), b0=csub(u0,u2);
  float2 a1=cadd(u1,u3), b1=cnegi(csub(u1,u3));
  float2 c0=cadd(v0,v2), d0=csub(v0,v2);
  float2 c1=cadd(v1,v3), d1=cnegi(csub(v1,v3));
  z[0]=cadd(a0,a1); z[4]=csub(a0,a1);
  z[2]=cadd(b0,b1); z[6]=csub(b0,b1);
  z[1]=cadd(c0,c1); z[5]=csub(c0,c1);
  z[3]=cadd(d0,d1); z[7]=csub(d0,d1);
}

// P1a v3: block = (b8, a). Reads FULL 3 KB rows (64 rows at stride 64*N2),
// stages as bf16 in LDS (B16: 64 x 386 uints), then 3 column-group passes of
// the 8x8 register FFT-64 with a bf16 LDS transpose scratch (S16: 64 x 130).
// ws1 layout identical to R8: [((b8*64+a)*3+cg)*8192 + kb*128 + c].
__global__ __launch_bounds__(1024) void p1a_kernel(const float* __restrict__ x,
                                                   unsigned* __restrict__ ws1) {
  extern __shared__ unsigned LDS[];
  unsigned* B16 = LDS;              // 64*386 uints (1 uint = bf16 re|im per ccol)
  unsigned* S16 = LDS + 64*386;     // 64*130 uints
  int bid = blockIdx.x;             // 512 = 8 * 64
  int b8 = bid >> 6, a = bid & 63;
  const int t = threadIdx.x, l = t & 63, w = t >> 6;

  // Load phase: wave w owns rows b = 4w..4w+3; 3 x 1 KB float4 instrs per row
  // cover the full contiguous 3 KB row. Convert f32 -> packed bf16 complex.
  const float* src = x + ((size_t)b8 * N1 + a) * N2;
  #pragma unroll
  for (int j = 0; j < 4; ++j) {
    int b = 4*w + j;
    const float* rp = src + (size_t)(64*b) * N2;
    float4 v0 = *reinterpret_cast<const float4*>(rp + 4*l);
    float4 v1 = *reinterpret_cast<const float4*>(rp + 4*(l+64));
    float4 v2 = *reinterpret_cast<const float4*>(rp + 4*(l+128));
    unsigned* br = B16 + b*386;
    *reinterpret_cast<uint2*>(br + 2*l) =
        make_uint2(pack_bf2(make_float2(v0.x,v0.y)), pack_bf2(make_float2(v0.z,v0.w)));
    *reinterpret_cast<uint2*>(br + 2*(l+64)) =
        make_uint2(pack_bf2(make_float2(v1.x,v1.y)), pack_bf2(make_float2(v1.z,v1.w)));
    *reinterpret_cast<uint2*>(br + 2*(l+128)) =
        make_uint2(pack_bf2(make_float2(v2.x,v2.y)), pack_bf2(make_float2(v2.z,v2.w)));
  }
  __syncthreads();

  const int c = t & 127, b0 = t >> 7;   // 128 ccols x 8 b0 = 1024 threads
  for (int pass = 0; pass < 3; ++pass) {
    // stage 1: gather column (pass*128 + c) over b = 8*b1 + b0; FFT-8 over b1
    float2 z[8];
    #pragma unroll
    for (int b1 = 0; b1 < 8; ++b1)
      z[b1] = unpack_bf2(B16[(8*b1 + b0)*386 + pass*128 + c]);
    fft8(z);
    {
      float sn, cs; __sincosf(-6.283185307179586f/64.f * (float)b0, &sn, &cs);
      float2 wstep = make_float2(cs, sn), wcur = wstep;
      #pragma unroll
      for (int j = 1; j < 8; ++j) { z[j] = cmul(z[j], wcur); wcur = cmul(wcur, wstep); }
    }
    __syncthreads();                   // prev pass's S16 reads complete
    #pragma unroll
    for (int j = 0; j < 8; ++j) S16[(j*8 + b0)*130 + c] = pack_bf2(z[j]);
    __syncthreads();                   // S16 write-back visible

    // stage 2: FFT-8 over b0 (fixed j = b0 var reused as jj), final twiddle, store
    const int jj = b0;
    #pragma unroll
    for (int i = 0; i < 8; ++i) z[i] = unpack_bf2(S16[(jj*8 + i)*130 + c]);
    fft8(z);                           // z[m] = FFT64 at kb = 8m+jj
    float2 wc, w8;
    { float sn, cs; __sincosf(-6.283185307179586f/4096.f * (float)(a*jj), &sn, &cs); wc = make_float2(cs, sn); }
    { float sn, cs; __sincosf(-6.283185307179586f/4096.f * (float)(8*a),  &sn, &cs); w8 = make_float2(cs, sn); }
    unsigned* wdst = ws1 + (((size_t)b8*64 + a)*3 + pass)*8192 + (size_t)jj*128 + c;
    #pragma unroll
    for (int m = 0; m < 8; ++m) {
      wdst[(size_t)m * 1024] = pack_bf2(cmul(z[m], wc));
      wc = cmul(wc, w8);
    }
  }
}

// P1b: FFT-64 over a for kb-pair {kb,64-kb}; Hermitian unpack; write packed
// plane ws2 (bf16): uint idx = (b8*4096 + r)*384 + col.
__global__ __launch_bounds__(1024) void p1b_kernel(const unsigned* __restrict__ ws1,
                                                   unsigned* __restrict__ ws2) {
  __shared__ float2 T[2][4096];
  int bid = blockIdx.x;                          // 1536 = 8*192
  int b8  = bid & 7;
  int rem = bid >> 3;
  int cg  = rem / 32, kbt = rem % 32;            // cg: 64-complex col group 0..5
  int kb0 = (kbt == 0) ? 0  : kbt;
  int kb1 = (kbt == 0) ? 32 : 64 - kbt;
  const int t = threadIdx.x, l = t & 63, wv = (t >> 6) & 7, ti = t >> 9;
  const int kb = ti ? kb1 : kb0;
  const int cgA = cg >> 1, chalf = (cg & 1) * 64;

  const unsigned* wsrc = ws1 + ((size_t)b8*64*3 + cgA)*8192
                             + (size_t)kb*128 + chalf + l;
  float2 z[8];
  #pragma unroll
  for (int a1 = 0; a1 < 8; ++a1)
    z[a1] = unpack_bf2(wsrc[(size_t)(8*a1 + wv) * 24576]);   // a*3*8192
  fft8(z);
  float fac = -6.283185307179586f/64.0f * (float)wv;
  #pragma unroll
  for (int q = 1; q < 8; ++q) {
    float sn, cs; __sincosf(fac * (float)q, &sn, &cs);
    z[q] = cmul(z[q], make_float2(cs, sn));
  }
  #pragma unroll
  for (int q = 0; q < 8; ++q) T[ti][(q*8 + wv)*64 + l] = z[q];
  __syncthreads();
  #pragma unroll
  for (int a0 = 0; a0 < 8; ++a0) z[a0] = T[ti][(wv*8 + a0)*64 + l];
  fft8(z);
  __syncthreads();
  #pragma unroll
  for (int ka1 = 0; ka1 < 8; ++ka1) T[ti][(8*ka1 + wv)*64 + l] = z[ka1];
  __syncthreads();

  unsigned* wout = ws2 + (size_t)b8 * N1 * NCC + (size_t)cg*64 + l;
  #pragma unroll
  for (int it = 0; it < 8; ++it) {
    int ka = 8*it + wv;
    int tj, kap;
    if (kbt == 0) { tj = ti; kap = ti ? (63 - ka) : ((64 - ka) & 63); }
    else          { tj = 1 - ti; kap = 63 - ka; }
    float2 Zk = T[ti][ka*64 + l];
    float2 Zp = T[tj][kap*64 + l];
    int r = kb + 64*ka;
    float2 o;
    if (r <= 2048) o = make_float2(0.5f*(Zk.x + Zp.x), 0.5f*(Zk.y + Zp.y));
    else           o = make_float2(0.5f*(Zp.y - Zk.y), 0.5f*(Zk.x - Zp.x));
    wout[(size_t)r * NCC] = pack_bf2(o);
  }
}

// Pass 2: FFT-768 per conjugate row pair, bf16 input plane, f32 out.
__global__ __launch_bounds__(256) void fft_hid_bf16(const unsigned* __restrict__ ws2,
                                                    float* __restrict__ out) {
  __shared__ float T[4][12*69];
  const int grp = threadIdx.x >> 6;
  const int l   = threadIdx.x & 63;
  int task = blockIdx.x * 4 + grp;              // 16392 = 4098*4
  int b  = task / 2049;
  int t1 = task - b * 2049;
  const bool special = (t1 == 0) || (t1 == 2048);
  const int mrow = special ? t1 : (N1 - t1);
  const unsigned short* pre16 = (const unsigned short*)ws2 + ((size_t)b*N1 + t1)*N2;
  const unsigned short* pim16 = (const unsigned short*)ws2 + ((size_t)b*N1 + mrow)*N2;

  float2 z[12];
  #pragma unroll
  for (int m = 0; m < 12; ++m) {
    float re = bf2f(pre16[(m << 6) + l]);
    float im = special ? 0.0f : bf2f(pim16[(m << 6) + l]);
    z[m] = make_float2(re, im);
  }

  float2 A[3][4];
  #pragma unroll
  for (int q = 0; q < 3; ++q) {
    float2 s0 = z[q], s1 = z[3+q], s2 = z[6+q], s3 = z[9+q];
    float2 t0 = cadd(s0,s2), t1v = csub(s0,s2);
    float2 t2 = cadd(s1,s3), t3 = cnegi(csub(s1,s3));
    A[q][0] = cadd(t0,t2); A[q][1] = cadd(t1v,t3);
    A[q][2] = csub(t0,t2); A[q][3] = csub(t1v,t3);
  }
  const float h3 = 0.8660254037844386f;
  const float2 W1[4] = { {1.f,0.f}, {h3,-0.5f}, {0.5f,-h3}, {0.f,-1.f} };
  const float2 W2[4] = { {1.f,0.f}, {0.5f,-h3}, {-0.5f,-h3}, {-1.f,0.f} };
  float2 y[12];
  #pragma unroll
  for (int k4 = 0; k4 < 4; ++k4) {
    float2 C0 = A[0][k4];
    float2 C1 = cmul(A[1][k4], W1[k4]);
    float2 C2 = cmul(A[2][k4], W2[k4]);
    float2 tt = cadd(C1,C2), d = csub(C1,C2);
    float2 u  = make_float2(C0.x - 0.5f*tt.x, C0.y - 0.5f*tt.y);
    float2 idd = make_float2(h3*d.y, -h3*d.x);
    y[k4]   = cadd(C0, tt);
    y[k4+4] = cadd(u, idd);
    y[k4+8] = csub(u, idd);
  }

  float base = -6.283185307179586f * (float)l / 768.0f;
  #pragma unroll
  for (int km = 1; km < 12; ++km) {
    float sn, cs; __sincosf(base * (float)km, &sn, &cs);
    y[km] = cmul(y[km], make_float2(cs, sn));
  }

  #pragma unroll
  for (int st = 0; st < 6; ++st) {
    int h = 32 >> st;
    int j = l & (h - 1);
    float sn, cs; __sincosf(-3.14159265358979f * (float)j / (float)h, &sn, &cs);
    float2 w = make_float2(cs, sn);
    bool hi = (l & h) != 0;
    #pragma unroll
    for (int m = 0; m < 12; ++m) {
      float px = __shfl_xor(y[m].x, h, 64);
      float py = __shfl_xor(y[m].y, h, 64);
      float2 p = make_float2(px, py);
      float2 lo  = cadd(y[m], p);
      float2 hiv = cmul(csub(p, y[m]), w);
      y[m] = hi ? hiv : lo;
    }
  }

  int r = ((l&1)<<5)|((l&2)<<3)|((l&4)<<1)|((l&8)>>1)|((l&16)>>3)|((l&32)>>5);
  float* Tb = T[grp];
  #pragma unroll
  for (int km = 0; km < 12; ++km) Tb[km*69 + r] = y[km].x;
  __syncthreads();

  float* pre = out + ((size_t)b*N1 + t1)*N2;
  float* pim = out + ((size_t)b*N1 + mrow)*N2;
  #pragma unroll
  for (int mp = 0; mp < 12; ++mp) {
    int k = (mp << 6) + l;
    float v = Tb[(k % 12)*69 + (k / 12)];
    pre[k] = v;
    if (!special) pim[(N2 - k) % N2] = v;
  }
}

// ---------------- fallback path (no workspace): fused f32 pass 1 + f32 hid ----------------
#define PADI(i) ((i) + ((i) >> 4))
#define CPBUF 4352

__device__ __forceinline__ void bfly4p(float2* arr, int base, int M, float fac, int np) {
  float2 a0 = arr[PADI(base)], a1 = arr[PADI(base+M)];
  float2 a2 = arr[PADI(base+2*M)], a3 = arr[PADI(base+3*M)];
  float2 t0 = cadd(a0,a2), t1 = csub(a0,a2);
  float2 t2 = cadd(a1,a3), t3 = cnegi(csub(a1,a3));
  float2 y0 = cadd(t0,t2), y1 = cadd(t1,t3), y2 = csub(t0,t2), y3 = csub(t1,t3);
  float ang = fac * (float)np;
  float sn, cs; __sincosf(ang, &sn, &cs);
  float2 w1 = make_float2(cs, sn);
  float2 w2 = cmul(w1,w1);
  float2 w3 = cmul(w2,w1);
  arr[PADI(base)]     = y0;
  arr[PADI(base+M)]   = cmul(y1,w1);
  arr[PADI(base+2*M)] = cmul(y2,w2);
  arr[PADI(base+3*M)] = cmul(y3,w3);
}

__global__ __launch_bounds__(1024) void fft_seq_fused(const float* __restrict__ x,
                                                      float* __restrict__ out) {
  extern __shared__ float2 lds[];
  int bid = blockIdx.x;
  int wg  = (bid & 7) * 96 + (bid >> 3);
  int b   = wg / 96;
  int g   = wg % 96;
  const int t = threadIdx.x;
  const size_t base = (size_t)b * N1 * N2 + 8 * (size_t)g;

  for (int r = t; r < N1; r += 1024) {
    const float* p = x + base + (size_t)r * N2;
    float4 A  = *reinterpret_cast<const float4*>(p);
    float4 Bv = *reinterpret_cast<const float4*>(p + 4);
    int ip = PADI(r);
    lds[ip]             = make_float2(A.x, A.y);
    lds[CPBUF + ip]     = make_float2(A.z, A.w);
    lds[2*CPBUF + ip]   = make_float2(Bv.x, Bv.y);
    lds[3*CPBUF + ip]   = make_float2(Bv.z, Bv.w);
  }
  __syncthreads();

  const int wv  = t >> 6;
  const int cp  = wv & 3;
  const int idx = ((wv >> 2) << 6) + (t & 63);
  float2* buf = lds + cp * CPBUF;

  #pragma unroll
  for (int s = 0; s < 6; ++s) {
    int lm = 10 - 2*s;
    int M  = 1 << lm;
    float fac = -6.283185307179586f / (float)(4*M);
    #pragma unroll
    for (int jj = 0; jj < 4; ++jj) {
      int j   = idx + (jj << 8);
      int np  = j & (M-1);
      int grp = j >> lm;
      int bse = (grp << (lm+2)) + np;
      bfly4p(buf, bse, M, fac, np);
    }
    __syncthreads();
  }

  float* orow = out + base;
  #pragma unroll
  for (int i = 0; i < 4; ++i) {
    int k  = ((t & 63) << 6) + (t >> 6) + (i << 4);
    int km = (N1 - k) & (N1 - 1);
    int pk = PADI(rev6(k));
    int pn = PADI(rev6(km));
    float o[8];
    #pragma unroll
    for (int c = 0; c < 4; ++c) {
      float2 zk = lds[c*CPBUF + pk];
      float2 zn = lds[c*CPBUF + pn];
      if (k <= 2048) { o[2*c] = 0.5f*(zk.x + zn.x); o[2*c+1] = 0.5f*(zk.y + zn.y); }
      else           { o[2*c] = 0.5f*(zn.y - zk.y); o[2*c+1] = 0.5f*(zk.x - zn.x); }
    }
    float* q = orow + (size_t)k * N2;
    *reinterpret_cast<float4*>(q)     = make_float4(o[0], o[1], o[2], o[3]);
    *reinterpret_cast<float4*>(q + 4) = make_float4(o[4], o[5], o[6], o[7]);
  }
}

__global__ __launch_bounds__(256) void fft_hid_f32(float* __restrict__ out) {
  __shared__ float T[4][12*69];
  const int grp = threadIdx.x >> 6;
  const int l   = threadIdx.x & 63;
  int task = blockIdx.x * 4 + grp;
  int b  = task / 2049;
  int t1 = task - b * 2049;
  const bool special = (t1 == 0) || (t1 == 2048);
  const int mrow = special ? t1 : (N1 - t1);
  float* baseB = out + (size_t)b * N1 * N2;
  float* pre = baseB + (size_t)t1 * N2;
  float* pim = baseB + (size_t)mrow * N2;

  float2 z[12];
  #pragma unroll
  for (int m = 0; m < 12; ++m) {
    float re = pre[(m << 6) + l];
    float im = special ? 0.0f : pim[(m << 6) + l];
    z[m] = make_float2(re, im);
  }

  float2 A[3][4];
  #pragma unroll
  for (int q = 0; q < 3; ++q) {
    float2 s0 = z[q], s1 = z[3+q], s2 = z[6+q], s3 = z[9+q];
    float2 t0 = cadd(s0,s2), t1v = csub(s0,s2);
    float2 t2 = cadd(s1,s3), t3 = cnegi(csub(s1,s3));
    A[q][0] = cadd(t0,t2); A[q][1] = cadd(t1v,t3);
    A[q][2] = csub(t0,t2); A[q][3] = csub(t1v,t3);
  }
  const float h3 = 0.8660254037844386f;
  const float2 W1[4] = { {1.f,0.f}, {h3,-0.5f}, {0.5f,-h3}, {0.f,-1.f} };
  const float2 W2[4] = { {1.f,0.f}, {0.5f,-h3}, {-0.5f,-h3}, {-1.f,0.f} };
  float2 y[12];
  #pragma unroll
  for (int k4 = 0; k4 < 4; ++k4) {
    float2 C0 = A[0][k4];
    float2 C1 = cmul(A[1][k4], W1[k4]);
    float2 C2 = cmul(A[2][k4], W2[k4]);
    float2 tt = cadd(C1,C2), d = csub(C1,C2);
    float2 u  = make_float2(C0.x - 0.5f*tt.x, C0.y - 0.5f*tt.y);
    float2 idd = make_float2(h3*d.y, -h3*d.x);
    y[k4]   = cadd(C0, tt);
    y[k4+4] = cadd(u, idd);
    y[k4+8] = csub(u, idd);
  }

  float base = -6.283185307179586f * (float)l / 768.0f;
  #pragma unroll
  for (int km = 1; km < 12; ++km) {
    float sn, cs; __sincosf(base * (float)km, &sn, &cs);
    y[km] = cmul(y[km], make_float2(cs, sn));
  }

  #pragma unroll
  for (int st = 0; st < 6; ++st) {
    int h = 32 >> st;
    int j = l & (h - 1);
    float sn, cs; __sincosf(-3.14159265358979f * (float)j / (float)h, &sn, &cs);
    float2 w = make_float2(cs, sn);
    bool hi = (l & h) != 0;
    #pragma unroll
    for (int m = 0; m < 12; ++m) {
      float px = __shfl_xor(y[m].x, h, 64);
      float py = __shfl_xor(y[m].y, h, 64);
      float2 p = make_float2(px, py);
      float2 lo  = cadd(y[m], p);
      float2 hiv = cmul(csub(p, y[m]), w);
      y[m] = hi ? hiv : lo;
    }
  }

  int r = ((l&1)<<5)|((l&2)<<3)|((l&4)<<1)|((l&8)>>1)|((l&16)>>3)|((l&32)>>5);
  float* Tb = T[grp];
  #pragma unroll
  for (int km = 0; km < 12; ++km) Tb[km*69 + r] = y[km].x;
  __syncthreads();

  #pragma unroll
  for (int mp = 0; mp < 12; ++mp) {
    int k = (mp << 6) + l;
    float v = Tb[(k % 12)*69 + (k / 12)];
    pre[k] = v;
    if (!special) pim[(N2 - k) % N2] = v;
  }
}

extern "C" void kernel_launch(void* const* d_in, const int* in_sizes, int n_in,
                              void* d_out, int out_size, void* d_ws, size_t ws_size,
                              hipStream_t stream) {
  const float* x = (const float*)d_in[0];
  float* out = (float*)d_out;
  if (ws_size >= WS_NEEDED) {
    unsigned* ws1 = (unsigned*)d_ws;
    unsigned* ws2 = ws1 + WS1_UINTS;
    (void)hipFuncSetAttribute(reinterpret_cast<const void*>(&p1a_kernel),
                              hipFuncAttributeMaxDynamicSharedMemorySize, P1A_LDS);
    p1a_kernel<<<dim3(512), dim3(1024), P1A_LDS, stream>>>(x, ws1);
    p1b_kernel<<<dim3(1536), dim3(1024), 0, stream>>>(ws1, ws2);
    fft_hid_bf16<<<dim3(4098), dim3(256), 0, stream>>>(ws2, out);
  } else {
    (void)hipFuncSetAttribute(reinterpret_cast<const void*>(&fft_seq_fused),
                              hipFuncAttributeMaxDynamicSharedMemorySize,
                              4 * CPBUF * (int)sizeof(float2));
    fft_seq_fused<<<dim3(768), dim3(1024), 4 * CPBUF * sizeof(float2), stream>>>(x, out);
    fft_hid_f32<<<dim3(4098), dim3(256), 0, stream>>>(out);
  }
}

// Round 11
// 95.470 us; speedup vs baseline: 1.0416x; 1.0416x over previous
//
#include <hip/hip_runtime.h>
#include <hip/hip_bf16.h>

#define N1 4096
#define N2 768
#define NCC 384
#define WS_NEEDED 100663296ull     // ws1 (50.3 MB bf16) + ws2 (50.3 MB bf16)
#define WS1_UINTS 12582912ull      // 8*64*3*8192

__device__ __forceinline__ float2 cadd(float2 a, float2 b){ return make_float2(a.x+b.x, a.y+b.y); }
__device__ __forceinline__ float2 csub(float2 a, float2 b){ return make_float2(a.x-b.x, a.y-b.y); }
__device__ __forceinline__ float2 cmul(float2 a, float2 b){ return make_float2(a.x*b.x - a.y*b.y, a.x*b.y + a.y*b.x); }
__device__ __forceinline__ float2 cnegi(float2 a){ return make_float2(a.y, -a.x); }  // -i * a

// bf16x2 pack/unpack (RTN)
__device__ __forceinline__ unsigned pack_bf2(float2 v) {
  unsigned ax = __float_as_uint(v.x); ax = (ax + 0x7FFFu + ((ax >> 16) & 1u)) >> 16;
  unsigned ay = __float_as_uint(v.y); ay = (ay + 0x7FFFu + ((ay >> 16) & 1u)) & 0xFFFF0000u;
  return ax | ay;
}
__device__ __forceinline__ float2 unpack_bf2(unsigned u) {
  return make_float2(__uint_as_float(u << 16), __uint_as_float(u & 0xFFFF0000u));
}
__device__ __forceinline__ float bf2f(unsigned short u) {
  return __uint_as_float((unsigned)u << 16);
}

__device__ __forceinline__ int rev6(int p) {
  int k = 0;
  #pragma unroll
  for (int i = 0; i < 6; ++i) { k = (k << 2) | (p & 3); p >>= 2; }
  return k;
}

// In-register DIF FFT-8, natural-order outputs.
__device__ __forceinline__ void fft8(float2 z[8]) {
  const float RH = 0.70710678118654752f;
  float2 u0=cadd(z[0],z[4]), v0=csub(z[0],z[4]);
  float2 u1=cadd(z[1],z[5]), v1=csub(z[1],z[5]);
  float2 u2=cadd(z[2],z[6]), v2=csub(z[2],z[6]);
  float2 u3=cadd(z[3],z[7]), v3=csub(z[3],z[7]);
  v1 = make_float2(RH*(v1.x+v1.y), RH*(v1.y-v1.x));
  v2 = cnegi(v2);
  v3 = make_float2(RH*(v3.y-v3.x), -RH*(v3.x+v3.y));
  float2 a0=cadd(u0,u2), b0=csub(u0,u2);
  float2 a1=cadd(u1,u3), b1=cnegi(csub(u1,u3));
  float2 c0=cadd(v0,v2), d0=csub(v0,v2);
  float2 c1=cadd(v1,v3), d1=cnegi(csub(v1,v3));
  z[0]=cadd(a0,a1); z[4]=csub(a0,a1);
  z[2]=cadd(b0,b1); z[6]=csub(b0,b1);
  z[1]=cadd(c0,c1); z[5]=csub(c0,c1);
  z[3]=cadd(d0,d1); z[7]=csub(d0,d1);
}

// P1a v6: pure-register, one WAVE per (b8, a, 64-ccol group). No LDS, no
// barriers (the hid-kernel recipe). Lane holds the whole 64-pt column:
// float2 Z[64] (static indices only). FFT-64 = 8x fft8 -> twiddle -> 8x fft8,
// the mid-transpose is free register renaming. f32 throughout; bf16 stores.
// ws1 layout identical to R8: [((b8*64+a)*3+cg)*8192 + kb*128 + cc].
__global__ __launch_bounds__(256) void p1a_kernel(const float* __restrict__ x,
                                                  unsigned* __restrict__ ws1) {
  const int t = threadIdx.x, l = t & 63, w = t >> 6;
  int job = blockIdx.x * 4 + w;            // 3072 = 8 * 64 * 6
  int b8  = job / 384;
  int rem = job - b8 * 384;
  int a   = rem / 6;
  int cw  = rem - a * 6;                   // 64-ccol group 0..5

  // 64 coalesced loads (512 B per wave instr), all in flight together.
  const float* src = x + ((size_t)(b8 * N1 + a)) * N2 + 2 * (cw * 64 + l);
  float2 Z[64];
  #pragma unroll
  for (int b = 0; b < 64; ++b)
    Z[b] = *reinterpret_cast<const float2*>(src + (size_t)b * 64 * N2);

  // stage 1: for each b0, FFT-8 over b1 (Z[8*b1+b0]), twiddle W64^{b0*k0},
  // write back Z[k0*8+b0]  (same index set per column -> in-place).
  #pragma unroll
  for (int b0 = 0; b0 < 8; ++b0) {
    float2 tt[8];
    #pragma unroll
    for (int b1 = 0; b1 < 8; ++b1) tt[b1] = Z[8 * b1 + b0];
    fft8(tt);
    float sn, cs; __sincosf(-6.283185307179586f / 64.f * (float)b0, &sn, &cs);
    float2 wstep = make_float2(cs, sn), wcur = wstep;
    #pragma unroll
    for (int k0 = 1; k0 < 8; ++k0) { tt[k0] = cmul(tt[k0], wcur); wcur = cmul(wcur, wstep); }
    #pragma unroll
    for (int k0 = 0; k0 < 8; ++k0) Z[k0 * 8 + b0] = tt[k0];
  }

  // stage 2: for each jj, FFT-8 over b0 (Z[jj*8+b0]) -> X[8m+jj];
  // final twiddle W4096^{a*(8m+jj)} via recurrence; stream bf16 stores.
  unsigned* wdst = ws1 + (((size_t)b8 * 64 + a) * 3 + (cw >> 1)) * 8192
                       + (size_t)((cw & 1) * 64 + l);
  #pragma unroll
  for (int jj = 0; jj < 8; ++jj) {
    float2 tt[8];
    #pragma unroll
    for (int b0 = 0; b0 < 8; ++b0) tt[b0] = Z[jj * 8 + b0];
    fft8(tt);
    float2 wc, w8;
    { float sn, cs; __sincosf(-6.283185307179586f/4096.f * (float)(a * jj), &sn, &cs); wc = make_float2(cs, sn); }
    { float sn, cs; __sincosf(-6.283185307179586f/4096.f * (float)(8 * a),  &sn, &cs); w8 = make_float2(cs, sn); }
    #pragma unroll
    for (int m = 0; m < 8; ++m) {
      wdst[(size_t)(8 * m + jj) * 128] = pack_bf2(cmul(tt[m], wc));
      wc = cmul(wc, w8);
    }
  }
}

// P1b: FFT-64 over a for kb-pair {kb,64-kb}; Hermitian unpack; write packed
// plane ws2 (bf16): uint idx = (b8*4096 + r)*384 + col.   (unchanged from R8)
__global__ __launch_bounds__(1024) void p1b_kernel(const unsigned* __restrict__ ws1,
                                                   unsigned* __restrict__ ws2) {
  __shared__ float2 T[2][4096];
  int bid = blockIdx.x;                          // 1536 = 8*192
  int b8  = bid & 7;
  int rem = bid >> 3;
  int cg  = rem / 32, kbt = rem % 32;            // cg: 64-complex col group 0..5
  int kb0 = (kbt == 0) ? 0  : kbt;
  int kb1 = (kbt == 0) ? 32 : 64 - kbt;
  const int t = threadIdx.x, l = t & 63, wv = (t >> 6) & 7, ti = t >> 9;
  const int kb = ti ? kb1 : kb0;
  const int cgA = cg >> 1, chalf = (cg & 1) * 64;

  const unsigned* wsrc = ws1 + ((size_t)b8*64*3 + cgA)*8192
                             + (size_t)kb*128 + chalf + l;
  float2 z[8];
  #pragma unroll
  for (int a1 = 0; a1 < 8; ++a1)
    z[a1] = unpack_bf2(wsrc[(size_t)(8*a1 + wv) * 24576]);   // a*3*8192
  fft8(z);
  float fac = -6.283185307179586f/64.0f * (float)wv;
  #pragma unroll
  for (int q = 1; q < 8; ++q) {
    float sn, cs; __sincosf(fac * (float)q, &sn, &cs);
    z[q] = cmul(z[q], make_float2(cs, sn));
  }
  #pragma unroll
  for (int q = 0; q < 8; ++q) T[ti][(q*8 + wv)*64 + l] = z[q];
  __syncthreads();
  #pragma unroll
  for (int a0 = 0; a0 < 8; ++a0) z[a0] = T[ti][(wv*8 + a0)*64 + l];
  fft8(z);
  __syncthreads();
  #pragma unroll
  for (int ka1 = 0; ka1 < 8; ++ka1) T[ti][(8*ka1 + wv)*64 + l] = z[ka1];
  __syncthreads();

  unsigned* wout = ws2 + (size_t)b8 * N1 * NCC + (size_t)cg*64 + l;
  #pragma unroll
  for (int it = 0; it < 8; ++it) {
    int ka = 8*it + wv;
    int tj, kap;
    if (kbt == 0) { tj = ti; kap = ti ? (63 - ka) : ((64 - ka) & 63); }
    else          { tj = 1 - ti; kap = 63 - ka; }
    float2 Zk = T[ti][ka*64 + l];
    float2 Zp = T[tj][kap*64 + l];
    int r = kb + 64*ka;
    float2 o;
    if (r <= 2048) o = make_float2(0.5f*(Zk.x + Zp.x), 0.5f*(Zk.y + Zp.y));
    else           o = make_float2(0.5f*(Zp.y - Zk.y), 0.5f*(Zk.x - Zp.x));
    wout[(size_t)r * NCC] = pack_bf2(o);
  }
}

// Pass 2: FFT-768 per conjugate row pair, bf16 input plane, f32 out. (unchanged)
__global__ __launch_bounds__(256) void fft_hid_bf16(const unsigned* __restrict__ ws2,
                                                    float* __restrict__ out) {
  __shared__ float T[4][12*69];
  const int grp = threadIdx.x >> 6;
  const int l   = threadIdx.x & 63;
  int task = blockIdx.x * 4 + grp;              // 16392 = 4098*4
  int b  = task / 2049;
  int t1 = task - b * 2049;
  const bool special = (t1 == 0) || (t1 == 2048);
  const int mrow = special ? t1 : (N1 - t1);
  const unsigned short* pre16 = (const unsigned short*)ws2 + ((size_t)b*N1 + t1)*N2;
  const unsigned short* pim16 = (const unsigned short*)ws2 + ((size_t)b*N1 + mrow)*N2;

  float2 z[12];
  #pragma unroll
  for (int m = 0; m < 12; ++m) {
    float re = bf2f(pre16[(m << 6) + l]);
    float im = special ? 0.0f : bf2f(pim16[(m << 6) + l]);
    z[m] = make_float2(re, im);
  }

  float2 A[3][4];
  #pragma unroll
  for (int q = 0; q < 3; ++q) {
    float2 s0 = z[q], s1 = z[3+q], s2 = z[6+q], s3 = z[9+q];
    float2 t0 = cadd(s0,s2), t1v = csub(s0,s2);
    float2 t2 = cadd(s1,s3), t3 = cnegi(csub(s1,s3));
    A[q][0] = cadd(t0,t2); A[q][1] = cadd(t1v,t3);
    A[q][2] = csub(t0,t2); A[q][3] = csub(t1v,t3);
  }
  const float h3 = 0.8660254037844386f;
  const float2 W1[4] = { {1.f,0.f}, {h3,-0.5f}, {0.5f,-h3}, {0.f,-1.f} };
  const float2 W2[4] = { {1.f,0.f}, {0.5f,-h3}, {-0.5f,-h3}, {-1.f,0.f} };
  float2 y[12];
  #pragma unroll
  for (int k4 = 0; k4 < 4; ++k4) {
    float2 C0 = A[0][k4];
    float2 C1 = cmul(A[1][k4], W1[k4]);
    float2 C2 = cmul(A[2][k4], W2[k4]);
    float2 tt = cadd(C1,C2), d = csub(C1,C2);
    float2 u  = make_float2(C0.x - 0.5f*tt.x, C0.y - 0.5f*tt.y);
    float2 idd = make_float2(h3*d.y, -h3*d.x);
    y[k4]   = cadd(C0, tt);
    y[k4+4] = cadd(u, idd);
    y[k4+8] = csub(u, idd);
  }

  float base = -6.283185307179586f * (float)l / 768.0f;
  #pragma unroll
  for (int km = 1; km < 12; ++km) {
    float sn, cs; __sincosf(base * (float)km, &sn, &cs);
    y[km] = cmul(y[km], make_float2(cs, sn));
  }

  #pragma unroll
  for (int st = 0; st < 6; ++st) {
    int h = 32 >> st;
    int j = l & (h - 1);
    float sn, cs; __sincosf(-3.14159265358979f * (float)j / (float)h, &sn, &cs);
    float2 w = make_float2(cs, sn);
    bool hi = (l & h) != 0;
    #pragma unroll
    for (int m = 0; m < 12; ++m) {
      float px = __shfl_xor(y[m].x, h, 64);
      float py = __shfl_xor(y[m].y, h, 64);
      float2 p = make_float2(px, py);
      float2 lo  = cadd(y[m], p);
      float2 hiv = cmul(csub(p, y[m]), w);
      y[m] = hi ? hiv : lo;
    }
  }

  int r = ((l&1)<<5)|((l&2)<<3)|((l&4)<<1)|((l&8)>>1)|((l&16)>>3)|((l&32)>>5);
  float* Tb = T[grp];
  #pragma unroll
  for (int km = 0; km < 12; ++km) Tb[km*69 + r] = y[km].x;
  __syncthreads();

  float* pre = out + ((size_t)b*N1 + t1)*N2;
  float* pim = out + ((size_t)b*N1 + mrow)*N2;
  #pragma unroll
  for (int mp = 0; mp < 12; ++mp) {
    int k = (mp << 6) + l;
    float v = Tb[(k % 12)*69 + (k / 12)];
    pre[k] = v;
    if (!special) pim[(N2 - k) % N2] = v;
  }
}

// ---------------- fallback path (no workspace): fused f32 pass 1 + f32 hid ----------------
#define PADI(i) ((i) + ((i) >> 4))
#define CPBUF 4352

__device__ __forceinline__ void bfly4p(float2* arr, int base, int M, float fac, int np) {
  float2 a0 = arr[PADI(base)], a1 = arr[PADI(base+M)];
  float2 a2 = arr[PADI(base+2*M)], a3 = arr[PADI(base+3*M)];
  float2 t0 = cadd(a0,a2), t1 = csub(a0,a2);
  float2 t2 = cadd(a1,a3), t3 = cnegi(csub(a1,a3));
  float2 y0 = cadd(t0,t2), y1 = cadd(t1,t3), y2 = csub(t0,t2), y3 = csub(t1,t3);
  float ang = fac * (float)np;
  float sn, cs; __sincosf(ang, &sn, &cs);
  float2 w1 = make_float2(cs, sn);
  float2 w2 = cmul(w1,w1);
  float2 w3 = cmul(w2,w1);
  arr[PADI(base)]     = y0;
  arr[PADI(base+M)]   = cmul(y1,w1);
  arr[PADI(base+2*M)] = cmul(y2,w2);
  arr[PADI(base+3*M)] = cmul(y3,w3);
}

__global__ __launch_bounds__(1024) void fft_seq_fused(const float* __restrict__ x,
                                                      float* __restrict__ out) {
  extern __shared__ float2 lds[];
  int bid = blockIdx.x;
  int wg  = (bid & 7) * 96 + (bid >> 3);
  int b   = wg / 96;
  int g   = wg % 96;
  const int t = threadIdx.x;
  const size_t base = (size_t)b * N1 * N2 + 8 * (size_t)g;

  for (int r = t; r < N1; r += 1024) {
    const float* p = x + base + (size_t)r * N2;
    float4 A  = *reinterpret_cast<const float4*>(p);
    float4 Bv = *reinterpret_cast<const float4*>(p + 4);
    int ip = PADI(r);
    lds[ip]             = make_float2(A.x, A.y);
    lds[CPBUF + ip]     = make_float2(A.z, A.w);
    lds[2*CPBUF + ip]   = make_float2(Bv.x, Bv.y);
    lds[3*CPBUF + ip]   = make_float2(Bv.z, Bv.w);
  }
  __syncthreads();

  const int wv  = t >> 6;
  const int cp  = wv & 3;
  const int idx = ((wv >> 2) << 6) + (t & 63);
  float2* buf = lds + cp * CPBUF;

  #pragma unroll
  for (int s = 0; s < 6; ++s) {
    int lm = 10 - 2*s;
    int M  = 1 << lm;
    float fac = -6.283185307179586f / (float)(4*M);
    #pragma unroll
    for (int jj = 0; jj < 4; ++jj) {
      int j   = idx + (jj << 8);
      int np  = j & (M-1);
      int grp = j >> lm;
      int bse = (grp << (lm+2)) + np;
      bfly4p(buf, bse, M, fac, np);
    }
    __syncthreads();
  }

  float* orow = out + base;
  #pragma unroll
  for (int i = 0; i < 4; ++i) {
    int k  = ((t & 63) << 6) + (t >> 6) + (i << 4);
    int km = (N1 - k) & (N1 - 1);
    int pk = PADI(rev6(k));
    int pn = PADI(rev6(km));
    float o[8];
    #pragma unroll
    for (int c = 0; c < 4; ++c) {
      float2 zk = lds[c*CPBUF + pk];
      float2 zn = lds[c*CPBUF + pn];
      if (k <= 2048) { o[2*c] = 0.5f*(zk.x + zn.x); o[2*c+1] = 0.5f*(zk.y + zn.y); }
      else           { o[2*c] = 0.5f*(zn.y - zk.y); o[2*c+1] = 0.5f*(zk.x - zn.x); }
    }
    float* q = orow + (size_t)k * N2;
    *reinterpret_cast<float4*>(q)     = make_float4(o[0], o[1], o[2], o[3]);
    *reinterpret_cast<float4*>(q + 4) = make_float4(o[4], o[5], o[6], o[7]);
  }
}

__global__ __launch_bounds__(256) void fft_hid_f32(float* __restrict__ out) {
  __shared__ float T[4][12*69];
  const int grp = threadIdx.x >> 6;
  const int l   = threadIdx.x & 63;
  int task = blockIdx.x * 4 + grp;
  int b  = task / 2049;
  int t1 = task - b * 2049;
  const bool special = (t1 == 0) || (t1 == 2048);
  const int mrow = special ? t1 : (N1 - t1);
  float* baseB = out + (size_t)b * N1 * N2;
  float* pre = baseB + (size_t)t1 * N2;
  float* pim = baseB + (size_t)mrow * N2;

  float2 z[12];
  #pragma unroll
  for (int m = 0; m < 12; ++m) {
    float re = pre[(m << 6) + l];
    float im = special ? 0.0f : pim[(m << 6) + l];
    z[m] = make_float2(re, im);
  }

  float2 A[3][4];
  #pragma unroll
  for (int q = 0; q < 3; ++q) {
    float2 s0 = z[q], s1 = z[3+q], s2 = z[6+q], s3 = z[9+q];
    float2 t0 = cadd(s0,s2), t1v = csub(s0,s2);
    float2 t2 = cadd(s1,s3), t3 = cnegi(csub(s1,s3));
    A[q][0] = cadd(t0,t2); A[q][1] = cadd(t1v,t3);
    A[q][2] = csub(t0,t2); A[q][3] = csub(t1v,t3);
  }
  const float h3 = 0.8660254037844386f;
  const float2 W1[4] = { {1.f,0.f}, {h3,-0.5f}, {0.5f,-h3}, {0.f,-1.f} };
  const float2 W2[4] = { {1.f,0.f}, {0.5f,-h3}, {-0.5f,-h3}, {-1.f,0.f} };
  float2 y[12];
  #pragma unroll
  for (int k4 = 0; k4 < 4; ++k4) {
    float2 C0 = A[0][k4];
    float2 C1 = cmul(A[1][k4], W1[k4]);
    float2 C2 = cmul(A[2][k4], W2[k4]);
    float2 tt = cadd(C1,C2), d = csub(C1,C2);
    float2 u  = make_float2(C0.x - 0.5f*tt.x, C0.y - 0.5f*tt.y);
    float2 idd = make_float2(h3*d.y, -h3*d.x);
    y[k4]   = cadd(C0, tt);
    y[k4+4] = cadd(u, idd);
    y[k4+8] = csub(u, idd);
  }

  float base = -6.283185307179586f * (float)l / 768.0f;
  #pragma unroll
  for (int km = 1; km < 12; ++km) {
    float sn, cs; __sincosf(base * (float)km, &sn, &cs);
    y[km] = cmul(y[km], make_float2(cs, sn));
  }

  #pragma unroll
  for (int st = 0; st < 6; ++st) {
    int h = 32 >> st;
    int j = l & (h - 1);
    float sn, cs; __sincosf(-3.14159265358979f * (float)j / (float)h, &sn, &cs);
    float2 w = make_float2(cs, sn);
    bool hi = (l & h) != 0;
    #pragma unroll
    for (int m = 0; m < 12; ++m) {
      float px = __shfl_xor(y[m].x, h, 64);
      float py = __shfl_xor(y[m].y, h, 64);
      float2 p = make_float2(px, py);
      float2 lo  = cadd(y[m], p);
      float2 hiv = cmul(csub(p, y[m]), w);
      y[m] = hi ? hiv : lo;
    }
  }

  int r = ((l&1)<<5)|((l&2)<<3)|((l&4)<<1)|((l&8)>>1)|((l&16)>>3)|((l&32)>>5);
  float* Tb = T[grp];
  #pragma unroll
  for (int km = 0; km < 12; ++km) Tb[km*69 + r] = y[km].x;
  __syncthreads();

  #pragma unroll
  for (int mp = 0; mp < 12; ++mp) {
    int k = (mp << 6) + l;
    float v = Tb[(k % 12)*69 + (k / 12)];
    pre[k] = v;
    if (!special) pim[(N2 - k) % N2] = v;
  }
}

extern "C" void kernel_launch(void* const* d_in, const int* in_sizes, int n_in,
                              void* d_out, int out_size, void* d_ws, size_t ws_size,
                              hipStream_t stream) {
  const float* x = (const float*)d_in[0];
  float* out = (float*)d_out;
  if (ws_size >= WS_NEEDED) {
    unsigned* ws1 = (unsigned*)d_ws;
    unsigned* ws2 = ws1 + WS1_UINTS;
    p1a_kernel<<<dim3(768), dim3(256), 0, stream>>>(x, ws1);
    p1b_kernel<<<dim3(1536), dim3(1024), 0, stream>>>(ws1, ws2);
    fft_hid_bf16<<<dim3(4098), dim3(256), 0, stream>>>(ws2, out);
  } else {
    (void)hipFuncSetAttribute(reinterpret_cast<const void*>(&fft_seq_fused),
                              hipFuncAttributeMaxDynamicSharedMemorySize,
                              4 * CPBUF * (int)sizeof(float2));
    fft_seq_fused<<<dim3(768), dim3(1024), 4 * CPBUF * sizeof(float2), stream>>>(x, out);
    fft_hid_f32<<<dim3(4098), dim3(256), 0, stream>>>(out);
  }
}